// Round 4
// baseline (496.532 us; speedup 1.0000x reference)
//
#include <hip/hip_runtime.h>
#include <cstdint>
#include <cstddef>

// Problem constants (FusedExperts: E=8 TOPK=2, B=2 S=4096 D=1024 H=2048)
#define TT   8192     // tokens = B*S
#define DD   1024     // model dim
#define HH   2048     // hidden dim
#define H2   4096     // 2*H
#define EE   8        // experts
#define PP   16384    // routed pairs = TT*TOPK
#define PADROWS 17280 // max sum of per-expert 128-padded group sizes = 135*128
#define MAXTILES 135

typedef unsigned short u16;
typedef __attribute__((ext_vector_type(8))) short bf16x8;   // 8 bf16 = 4 VGPR (MFMA A/B frag)
typedef __attribute__((ext_vector_type(8))) unsigned short u16x8;
typedef __attribute__((ext_vector_type(4))) float f32x4;    // MFMA C/D frag

__device__ __forceinline__ u16 f2bf(float f) {
  unsigned int u = __builtin_bit_cast(unsigned int, f);
  u += 0x7fffu + ((u >> 16) & 1u);          // round-to-nearest-even
  return (u16)(u >> 16);
}
__device__ __forceinline__ float bf2f(u16 s) {
  unsigned int u = ((unsigned int)s) << 16;
  return __builtin_bit_cast(float, u);
}

__device__ __forceinline__ void gload_lds16(const u16* g, u16* l) {
  __builtin_amdgcn_global_load_lds(
      (const __attribute__((address_space(1))) void*)g,
      (__attribute__((address_space(3))) void*)l, 16, 0, 0);
}

// counted-vmcnt pipeline sync (T4): never drain to 0 in the main loop
#define WAITV8() asm volatile("s_waitcnt vmcnt(8)" ::: "memory")
#define WAITV0() asm volatile("s_waitcnt vmcnt(0)" ::: "memory")
#define SBAR()  { __builtin_amdgcn_sched_barrier(0); __builtin_amdgcn_s_barrier(); __builtin_amdgcn_sched_barrier(0); }

// ---------------- casts ----------------
__global__ void cast_x_kernel(const float* __restrict__ x, u16* __restrict__ xb) {
  const long i = (long)blockIdx.x * 256 + threadIdx.x;  // one thread -> 8 elems
  const f32x4* s = (const f32x4*)(x + i * 8);
  f32x4 a = s[0], b = s[1];
  u16x8 o;
  o[0]=f2bf(a[0]); o[1]=f2bf(a[1]); o[2]=f2bf(a[2]); o[3]=f2bf(a[3]);
  o[4]=f2bf(b[0]); o[5]=f2bf(b[1]); o[6]=f2bf(b[2]); o[7]=f2bf(b[3]);
  *(u16x8*)(xb + i * 8) = o;
}

// src [E][R][C] f32 -> dst [E][C][R] bf16, vectorized 256B-contiguous writes.
// Tile: 128 src-rows x 32 src-cols. LDS [32][140] u16 (280B row = 70 dwords;
// gcd(70,32)=2 -> 2-way bank alias on phase-1 transposed writes = free).
__global__ void tcast_kernel(const float* __restrict__ src, u16* __restrict__ dst,
                             int R, int C) {
  __shared__ __align__(16) u16 tile[32][140];
  const long base = (long)blockIdx.z * (long)R * C;
  const int c0 = blockIdx.x * 32, r0 = blockIdx.y * 128;
  const int t = threadIdx.x;
  {
    const int tx = t & 31;          // col
    const int ty = t >> 5;          // row 0..7 (+8*rr)
#pragma unroll
    for (int rr = 0; rr < 16; ++rr) {
      const int r = ty + rr * 8;
      tile[tx][r] = f2bf(src[base + (long)(r0 + r) * C + c0 + tx]);
    }
  }
  __syncthreads();
  {
    const int k = t & 15;           // chunk within row: r8 = 8k
    const int cb = t >> 4;          // 0..15
#pragma unroll
    for (int i = 0; i < 2; ++i) {
      const int c = i * 16 + cb;
      u16x8 o = *(const u16x8*)(&tile[c][8 * k]);
      *(u16x8*)(dst + base + (long)(c0 + c) * R + r0 + 8 * k) = o;
    }
  }
}

// ---------------- routing ----------------
__global__ void count_kernel(const int* __restrict__ eidx, int* __restrict__ cnt) {
  int i = blockIdx.x * 256 + threadIdx.x;
  if (i < PP) atomicAdd(&cnt[eidx[i]], 1);
}
__global__ void scan_kernel(const int* __restrict__ cnt, int* __restrict__ pofs) {
  if (threadIdx.x == 0 && blockIdx.x == 0) {
    int run = 0;
    for (int e = 0; e < EE; ++e) { pofs[e] = run; run += ((cnt[e] + 127) >> 7) << 7; }
    pofs[EE] = run;
  }
}
__global__ void place_kernel(const int* __restrict__ eidx, const float* __restrict__ p,
                             const int* __restrict__ pofs, int* __restrict__ cnt2,
                             int* __restrict__ ptok, float* __restrict__ pscale,
                             int* __restrict__ ppos) {
  int i = blockIdx.x * 256 + threadIdx.x;
  if (i < PP) {
    int e = eidx[i];
    int r = atomicAdd(&cnt2[e], 1);
    int pos = pofs[e] + r;
    ptok[pos] = i >> 1;       // token index (TOPK=2)
    pscale[pos] = p[i];
    ppos[i] = pos;
  }
}

// ============ GEMM cores: 128x128 tile, T2 XOR swizzle, T1 XCD swizzle,
// ============ double-buffered LDS + counted vmcnt(8) pipeline (T3-min+T4), T5 setprio.
// LDS tile [128][64] bf16; (row, slot) stored at slot' = slot ^ (row&7).
// global_load_lds writes linearly -> per-lane GLOBAL source inverse-swizzled.
// Pipeline per K-tile t: WAITV(8) -> bar -> compute(buf[t&1]) -> bar -> STAGE(t+2 -> buf[t&1]).
// Safety: vmcnt is an in-order FIFO per wave; ds_reads retire before barrier arrival
// (they feed MFMAs via compiler lgkmcnt), so overwriting buf[t&1] after the barrier is WAR-safe.

// GEMM1: hb[pos, 0:H] = silu(g)*h where hg = x[tok] @ w13[e]
__global__ __launch_bounds__(256, 2)
void gemm1_kernel(const u16* __restrict__ xb, const u16* __restrict__ w13t,
                  const int* __restrict__ ptok, const int* __restrict__ pofs,
                  u16* __restrict__ hb) {
  __shared__ __align__(16) u16 lds_a[2 * 128 * 64];
  __shared__ __align__(16) u16 lds_b[2 * 128 * 64];

  // T1 XCD swizzle: nwg = 135*32 = 4320 = 8*540 (exact)
  const int f = blockIdx.y * MAXTILES + blockIdx.x;
  const int wg = (f & 7) * 540 + (f >> 3);
  const int tileIdx = wg % MAXTILES;
  const int j = wg / MAXTILES;                 // h cols [j*64, j*64+64)

  const int ts = tileIdx * 128;
  if (ts >= pofs[EE]) return;
  int e = 0;
#pragma unroll
  for (int i = 1; i < EE; ++i) e += (ts >= pofs[i]) ? 1 : 0;

  const int tid = threadIdx.x;
  const int w = tid >> 6, lane = tid & 63;
  const int wr = w >> 1, wc = w & 1;

  const u16* bbase = w13t + (long)e * ((long)H2 * DD);

  // --- staging setup: 4 rounds each of A and B; 16 B per lane per round ---
  const u16* asrc[4]; const u16* bsrc[4];
  int sdoff[4];
#pragma unroll
  for (int r = 0; r < 4; ++r) {
    const int L = (r * 4 + w) * 1024 + lane * 16;       // linear LDS byte
    const int row = L >> 7;                              // 128 B per row
    const int slot = ((L >> 4) & 7) ^ (row & 7);         // inverse-swizzled src slot
    asrc[r] = xb + (long)ptok[ts + row] * DD + slot * 8;
    const int gr = (row < 64) ? (j * 64 + row) : (HH + j * 64 + row - 64);
    bsrc[r] = bbase + (long)gr * DD + slot * 8;
    sdoff[r] = (r * 4 + w) * 512;                        // wave-uniform dst offset (u16)
  }

  // --- fragment read offsets (u16 units), swizzled ---
  const int rA = wr * 64 + (lane & 15);
  const int sA = lane >> 4;
  const int x7 = lane & 7;
  int aoff[2][4], boff[2][4];
  int rB[4];
  rB[0] = wc * 32 + (lane & 15);
  rB[1] = wc * 32 + 16 + (lane & 15);
  rB[2] = 64 + wc * 32 + (lane & 15);
  rB[3] = 64 + wc * 32 + 16 + (lane & 15);
#pragma unroll
  for (int kk = 0; kk < 2; ++kk) {
    const int sl = ((kk * 4 + sA) ^ x7) * 8;
#pragma unroll
    for (int m = 0; m < 4; ++m) aoff[kk][m] = (rA + m * 16) * 64 + sl;
#pragma unroll
    for (int n = 0; n < 4; ++n) boff[kk][n] = rB[n] * 64 + sl;
  }

  f32x4 acc[4][4];
#pragma unroll
  for (int m = 0; m < 4; ++m)
#pragma unroll
    for (int n = 0; n < 4; ++n) acc[m][n] = (f32x4){0.f, 0.f, 0.f, 0.f};

  auto stage = [&](int t, int par) {
    const int k0 = t * 64;
    u16* la = lds_a + par * 8192;
    u16* lb = lds_b + par * 8192;
#pragma unroll
    for (int r = 0; r < 4; ++r) gload_lds16(asrc[r] + k0, la + sdoff[r]);
#pragma unroll
    for (int r = 0; r < 4; ++r) gload_lds16(bsrc[r] + k0, lb + sdoff[r]);
  };
  auto compute = [&](int par) {
    const u16* la = lds_a + par * 8192;
    const u16* lb = lds_b + par * 8192;
    bf16x8 af[2][4], bfr[2][4];
#pragma unroll
    for (int kk = 0; kk < 2; ++kk) {
#pragma unroll
      for (int m = 0; m < 4; ++m) af[kk][m] = *(const bf16x8*)(la + aoff[kk][m]);
#pragma unroll
      for (int n = 0; n < 4; ++n) bfr[kk][n] = *(const bf16x8*)(lb + boff[kk][n]);
    }
    __builtin_amdgcn_s_setprio(1);
#pragma unroll
    for (int m = 0; m < 4; ++m)
#pragma unroll
      for (int n = 0; n < 4; ++n)
#pragma unroll
        for (int kk = 0; kk < 2; ++kk)
          acc[m][n] = __builtin_amdgcn_mfma_f32_16x16x32_bf16(af[kk][m], bfr[kk][n], acc[m][n], 0, 0, 0);
    __builtin_amdgcn_s_setprio(0);
  };

  // NT = 16 K-tiles of 64
  stage(0, 0); stage(1, 1);
#pragma unroll 2
  for (int t = 0; t < 14; ++t) {
    WAITV8(); SBAR();
    compute(t & 1);
    SBAR();
    stage(t + 2, t & 1);
  }
  WAITV8(); SBAR(); compute(0); SBAR();   // t=14
  WAITV0(); SBAR(); compute(1);           // t=15

  // epilogue: silu(g)*h in registers (n-frag pairs (0,2) and (1,3) share cols)
  const int rg = lane >> 4;              // C/D: row = rg*4 + r, col = lane&15
#pragma unroll
  for (int m = 0; m < 4; ++m)
#pragma unroll
    for (int n = 0; n < 2; ++n) {
      const int col = j * 64 + wc * 32 + n * 16 + (lane & 15);
#pragma unroll
      for (int r = 0; r < 4; ++r) {
        const int row = ts + wr * 64 + m * 16 + rg * 4 + r;
        const float h = acc[m][n][r];
        const float g = acc[m][n + 2][r];
        hb[(long)row * HH + col] = f2bf(h * (g / (1.f + __expf(-g))));
      }
    }
}

// GEMM2: ye[pos,:] = pscale[pos] * (hb[pos,:] @ w2t[e]^T), tile 128x128
__global__ __launch_bounds__(256, 2)
void gemm2_kernel(const u16* __restrict__ hb, const u16* __restrict__ w2t,
                  const float* __restrict__ pscale, const int* __restrict__ pofs,
                  u16* __restrict__ ye) {
  __shared__ __align__(16) u16 lds_a[2 * 128 * 64];
  __shared__ __align__(16) u16 lds_b[2 * 128 * 64];

  // T1 XCD swizzle: nwg = 135*8 = 1080 = 8*135 (exact)
  const int f = blockIdx.y * MAXTILES + blockIdx.x;
  const int wg = (f & 7) * 135 + (f >> 3);
  const int tileIdx = wg % MAXTILES;
  const int j = wg / MAXTILES;                 // out cols [j*128, j*128+128)

  const int ts = tileIdx * 128;
  if (ts >= pofs[EE]) return;
  int e = 0;
#pragma unroll
  for (int i = 1; i < EE; ++i) e += (ts >= pofs[i]) ? 1 : 0;

  const int tid = threadIdx.x;
  const int w = tid >> 6, lane = tid & 63;
  const int wr = w >> 1, wc = w & 1;

  const u16* bbase = w2t + (long)e * ((long)DD * HH);

  const u16* asrc[4]; const u16* bsrc[4];
  int sdoff[4];
#pragma unroll
  for (int r = 0; r < 4; ++r) {
    const int L = (r * 4 + w) * 1024 + lane * 16;
    const int row = L >> 7;
    const int slot = ((L >> 4) & 7) ^ (row & 7);
    asrc[r] = hb + (long)(ts + row) * HH + slot * 8;
    bsrc[r] = bbase + (long)(j * 128 + row) * HH + slot * 8;
    sdoff[r] = (r * 4 + w) * 512;
  }

  const int rA = wr * 64 + (lane & 15);
  const int sA = lane >> 4;
  const int x7 = lane & 7;
  int aoff[2][4], boff[2][4];
#pragma unroll
  for (int kk = 0; kk < 2; ++kk) {
    const int sl = ((kk * 4 + sA) ^ x7) * 8;
#pragma unroll
    for (int m = 0; m < 4; ++m) aoff[kk][m] = (rA + m * 16) * 64 + sl;
#pragma unroll
    for (int n = 0; n < 4; ++n) boff[kk][n] = (wc * 64 + n * 16 + (lane & 15)) * 64 + sl;
  }

  f32x4 acc[4][4];
#pragma unroll
  for (int m = 0; m < 4; ++m)
#pragma unroll
    for (int n = 0; n < 4; ++n) acc[m][n] = (f32x4){0.f, 0.f, 0.f, 0.f};

  auto stage = [&](int t, int par) {
    const int k0 = t * 64;
    u16* la = lds_a + par * 8192;
    u16* lb = lds_b + par * 8192;
#pragma unroll
    for (int r = 0; r < 4; ++r) gload_lds16(asrc[r] + k0, la + sdoff[r]);
#pragma unroll
    for (int r = 0; r < 4; ++r) gload_lds16(bsrc[r] + k0, lb + sdoff[r]);
  };
  auto compute = [&](int par) {
    const u16* la = lds_a + par * 8192;
    const u16* lb = lds_b + par * 8192;
    bf16x8 af[2][4], bfr[2][4];
#pragma unroll
    for (int kk = 0; kk < 2; ++kk) {
#pragma unroll
      for (int m = 0; m < 4; ++m) af[kk][m] = *(const bf16x8*)(la + aoff[kk][m]);
#pragma unroll
      for (int n = 0; n < 4; ++n) bfr[kk][n] = *(const bf16x8*)(lb + boff[kk][n]);
    }
    __builtin_amdgcn_s_setprio(1);
#pragma unroll
    for (int m = 0; m < 4; ++m)
#pragma unroll
      for (int n = 0; n < 4; ++n)
#pragma unroll
        for (int kk = 0; kk < 2; ++kk)
          acc[m][n] = __builtin_amdgcn_mfma_f32_16x16x32_bf16(af[kk][m], bfr[kk][n], acc[m][n], 0, 0, 0);
    __builtin_amdgcn_s_setprio(0);
  };

  // NT = 32 K-tiles of 64
  stage(0, 0); stage(1, 1);
#pragma unroll 2
  for (int t = 0; t < 30; ++t) {
    WAITV8(); SBAR();
    compute(t & 1);
    SBAR();
    stage(t + 2, t & 1);
  }
  WAITV8(); SBAR(); compute(0); SBAR();   // t=30
  WAITV0(); SBAR(); compute(1);           // t=31

  const int rg = lane >> 4;
#pragma unroll
  for (int m = 0; m < 4; ++m)
#pragma unroll
    for (int r = 0; r < 4; ++r) {
      const int row = ts + wr * 64 + m * 16 + rg * 4 + r;
      const float sc = pscale[row];   // 0.0 for pad rows
#pragma unroll
      for (int n = 0; n < 4; ++n) {
        const int col = j * 128 + wc * 64 + n * 16 + (lane & 15);
        ye[(long)row * DD + col] = f2bf(acc[m][n][r] * sc);
      }
    }
}

// ---------------- combine: y[t] = ye[pos0] + ye[pos1] ----------------
__global__ void combine_kernel(const u16* __restrict__ ye, const int* __restrict__ ppos,
                               float* __restrict__ y) {
  const long i = (long)blockIdx.x * 256 + threadIdx.x;  // one thread -> 8 outputs
  const int t = (int)(i >> 7);
  const int c = ((int)i & 127) * 8;
  const int p0 = ppos[t * 2], p1 = ppos[t * 2 + 1];
  u16x8 v0 = *(const u16x8*)(ye + (long)p0 * DD + c);
  u16x8 v1 = *(const u16x8*)(ye + (long)p1 * DD + c);
  f32x4 o0, o1;
  o0[0] = bf2f(v0[0]) + bf2f(v1[0]);
  o0[1] = bf2f(v0[1]) + bf2f(v1[1]);
  o0[2] = bf2f(v0[2]) + bf2f(v1[2]);
  o0[3] = bf2f(v0[3]) + bf2f(v1[3]);
  o1[0] = bf2f(v0[4]) + bf2f(v1[4]);
  o1[1] = bf2f(v0[5]) + bf2f(v1[5]);
  o1[2] = bf2f(v0[6]) + bf2f(v1[6]);
  o1[3] = bf2f(v0[7]) + bf2f(v1[7]);
  *(f32x4*)(y + (long)t * DD + c) = o0;
  *(f32x4*)(y + (long)t * DD + c + 4) = o1;
}

extern "C" void kernel_launch(void* const* d_in, const int* in_sizes, int n_in,
                              void* d_out, int out_size, void* d_ws, size_t ws_size,
                              hipStream_t stream) {
  const float* x    = (const float*)d_in[0];
  const float* ep   = (const float*)d_in[1];
  const int*   eidx = (const int*)d_in[2];
  const float* w13  = (const float*)d_in[3];
  const float* w2   = (const float*)d_in[4];
  float* y = (float*)d_out;

  char* ws = (char*)d_ws;
  size_t off = 0;
  auto alloc = [&](size_t bytes) {
    char* p = ws + off;
    off = (off + bytes + 255) & ~(size_t)255;
    return p;
  };
  u16* xb     = (u16*)alloc((size_t)TT * DD * 2);
  u16* w13t   = (u16*)alloc((size_t)EE * H2 * DD * 2);
  u16* w2t    = (u16*)alloc((size_t)EE * DD * HH * 2);
  u16* hb     = (u16*)alloc((size_t)PADROWS * HH * 2);
  u16* ye     = (u16*)alloc((size_t)PADROWS * DD * 2);
  char* zbase = ws + off;
  int*   ptok   = (int*)alloc((size_t)PADROWS * 4);
  float* pscale = (float*)alloc((size_t)PADROWS * 4);
  int*   cnt    = (int*)alloc(EE * 4);
  int*   cnt2   = (int*)alloc(EE * 4);
  size_t zbytes = (size_t)((ws + off) - zbase);
  int*   pofs   = (int*)alloc((EE + 1) * 4);
  int*   ppos   = (int*)alloc((size_t)PP * 4);
  (void)ws_size; (void)in_sizes; (void)n_in; (void)out_size;

  // zero routing state (pad rows -> token 0, scale 0)
  hipMemsetAsync(zbase, 0, zbytes, stream);

  cast_x_kernel<<<4096, 256, 0, stream>>>(x, xb);
  // w13 [E][1024][4096] -> w13t [E][4096][1024]
  tcast_kernel<<<dim3(H2 / 32, DD / 128, EE), 256, 0, stream>>>(w13, w13t, DD, H2);
  // w2 [E][2048][1024] -> w2t [E][1024][2048]
  tcast_kernel<<<dim3(DD / 32, HH / 128, EE), 256, 0, stream>>>(w2, w2t, HH, DD);

  count_kernel<<<PP / 256, 256, 0, stream>>>(eidx, cnt);
  scan_kernel<<<1, 64, 0, stream>>>(cnt, pofs);
  place_kernel<<<PP / 256, 256, 0, stream>>>(eidx, ep, pofs, cnt2, ptok, pscale, ppos);

  gemm1_kernel<<<dim3(MAXTILES, HH / 64), 256, 0, stream>>>(xb, w13t, ptok, pofs, hb);
  gemm2_kernel<<<dim3(MAXTILES, DD / 128), 256, 0, stream>>>(hb, w2t, pscale, pofs, ye);
  combine_kernel<<<4096, 256, 0, stream>>>(ye, ppos, y);
}

// Round 5
// 478.038 us; speedup vs baseline: 1.0387x; 1.0387x over previous
//
#include <hip/hip_runtime.h>
#include <cstdint>
#include <cstddef>

// Problem constants (FusedExperts: E=8 TOPK=2, B=2 S=4096 D=1024 H=2048)
#define TT   8192     // tokens = B*S
#define DD   1024     // model dim
#define HH   2048     // hidden dim
#define H2   4096     // 2*H
#define EE   8        // experts
#define PP   16384    // routed pairs = TT*TOPK
#define PADROWS 18432 // max sum of per-expert 256-padded group sizes = 72*256
#define MAXT1 72      // 256-row tiles (gemm1)
#define MAXT2 144     // 128-row tiles (gemm2)

typedef unsigned short u16;
typedef __attribute__((ext_vector_type(8))) short bf16x8;   // 8 bf16 = 4 VGPR (MFMA A/B frag)
typedef __attribute__((ext_vector_type(8))) unsigned short u16x8;
typedef __attribute__((ext_vector_type(4))) float f32x4;    // MFMA C/D frag

__device__ __forceinline__ u16 f2bf(float f) {
  unsigned int u = __builtin_bit_cast(unsigned int, f);
  u += 0x7fffu + ((u >> 16) & 1u);          // round-to-nearest-even
  return (u16)(u >> 16);
}
__device__ __forceinline__ float bf2f(u16 s) {
  unsigned int u = ((unsigned int)s) << 16;
  return __builtin_bit_cast(float, u);
}

__device__ __forceinline__ void gload_lds16(const u16* g, u16* l) {
  __builtin_amdgcn_global_load_lds(
      (const __attribute__((address_space(1))) void*)g,
      (__attribute__((address_space(3))) void*)l, 16, 0, 0);
}

#define BAR()   { __builtin_amdgcn_sched_barrier(0); __builtin_amdgcn_s_barrier(); __builtin_amdgcn_sched_barrier(0); }
#define LGKM0() { asm volatile("s_waitcnt lgkmcnt(0)" ::: "memory"); __builtin_amdgcn_sched_barrier(0); }
#define WAITV4() asm volatile("s_waitcnt vmcnt(4)" ::: "memory")
#define WAITV0() asm volatile("s_waitcnt vmcnt(0)" ::: "memory")

// ---------------- casts ----------------
__global__ void cast_x_kernel(const float* __restrict__ x, u16* __restrict__ xb) {
  const long i = (long)blockIdx.x * 256 + threadIdx.x;  // one thread -> 8 elems
  const f32x4* s = (const f32x4*)(x + i * 8);
  f32x4 a = s[0], b = s[1];
  u16x8 o;
  o[0]=f2bf(a[0]); o[1]=f2bf(a[1]); o[2]=f2bf(a[2]); o[3]=f2bf(a[3]);
  o[4]=f2bf(b[0]); o[5]=f2bf(b[1]); o[6]=f2bf(b[2]); o[7]=f2bf(b[3]);
  *(u16x8*)(xb + i * 8) = o;
}

// src [E][R][C] f32 -> dst [E][C][R] bf16, vectorized 256B-contiguous writes.
__global__ void tcast_kernel(const float* __restrict__ src, u16* __restrict__ dst,
                             int R, int C) {
  __shared__ __align__(16) u16 tile[32][140];
  const long base = (long)blockIdx.z * (long)R * C;
  const int c0 = blockIdx.x * 32, r0 = blockIdx.y * 128;
  const int t = threadIdx.x;
  {
    const int tx = t & 31;          // col
    const int ty = t >> 5;          // row 0..7 (+8*rr)
#pragma unroll
    for (int rr = 0; rr < 16; ++rr) {
      const int r = ty + rr * 8;
      tile[tx][r] = f2bf(src[base + (long)(r0 + r) * C + c0 + tx]);
    }
  }
  __syncthreads();
  {
    const int k = t & 15;           // chunk within row: r8 = 8k
    const int cb = t >> 4;          // 0..15
#pragma unroll
    for (int i = 0; i < 2; ++i) {
      const int c = i * 16 + cb;
      u16x8 o = *(const u16x8*)(&tile[c][8 * k]);
      *(u16x8*)(dst + base + (long)(c0 + c) * R + r0 + 8 * k) = o;
    }
  }
}

// ---------------- routing ----------------
__global__ void count_kernel(const int* __restrict__ eidx, int* __restrict__ cnt) {
  int i = blockIdx.x * 256 + threadIdx.x;
  if (i < PP) atomicAdd(&cnt[eidx[i]], 1);
}
__global__ void scan_kernel(const int* __restrict__ cnt, int* __restrict__ pofs) {
  if (threadIdx.x == 0 && blockIdx.x == 0) {
    int run = 0;
    for (int e = 0; e < EE; ++e) { pofs[e] = run; run += ((cnt[e] + 255) >> 8) << 8; }
    pofs[EE] = run;
  }
}
__global__ void place_kernel(const int* __restrict__ eidx, const float* __restrict__ p,
                             const int* __restrict__ pofs, int* __restrict__ cnt2,
                             int* __restrict__ ptok, float* __restrict__ pscale,
                             int* __restrict__ ppos) {
  int i = blockIdx.x * 256 + threadIdx.x;
  if (i < PP) {
    int e = eidx[i];
    int r = atomicAdd(&cnt2[e], 1);
    int pos = pofs[e] + r;
    ptok[pos] = i >> 1;       // token index (TOPK=2)
    pscale[pos] = p[i];
    ppos[i] = pos;
  }
}

// ============ GEMM1: 256x256 8-phase schedule (m201 template port) ============
// BM=256 rows, B-tile = 256 rows of w13t (128 h + 128 g, interleaved in 32-col
// stripes per wave), BK=64, 512 threads = 2(M) x 4(N) waves, per-wave 128x64.
// LDS 128KB: A[p][ht]=[128][64] swz, B[p][ht] likewise at +32768 (u16 units).
// Swizzle: (row,slot) stored at slot^(row&7); gload_lds linear dest + inverse-
// swizzled global source; ds_read applies same XOR (proven R2-R3).
// Phases per K-tile t (p=t&1): P0{ds a03,b01; stage B0(t+1)->p^1} P1{ds a47;
// stage B1(t+1)} P2{ds b23; stage A0(t+2)->p} P3{stage A1(t+2); vmcnt(4)}.
// Each phase: issue -> barrier -> lgkmcnt(0) -> prio1 -> 16 MFMA -> prio0 -> barrier.
// FIFO ledger: at t.P3 tail, waiting vmcnt(4) retires ...B1(t+1); leaves A(t+2).
#define QUAD(M0, N0) do {                                                        \
    __builtin_amdgcn_s_setprio(1);                                               \
    _Pragma("unroll") for (int mm = 0; mm < 4; ++mm)                             \
    _Pragma("unroll") for (int nn = 0; nn < 2; ++nn)                             \
    _Pragma("unroll") for (int kk = 0; kk < 2; ++kk)                             \
      acc[(M0)+mm][(N0)+nn] = __builtin_amdgcn_mfma_f32_16x16x32_bf16(           \
          af[kk][(M0)+mm], bf[kk][(N0)+nn], acc[(M0)+mm][(N0)+nn], 0, 0, 0);     \
    __builtin_amdgcn_s_setprio(0);                                               \
  } while (0)

__global__ __launch_bounds__(512, 2)
void gemm1_kernel(const u16* __restrict__ xb, const u16* __restrict__ w13t,
                  const int* __restrict__ ptok, const int* __restrict__ pofs,
                  u16* __restrict__ hb) {
  __shared__ __align__(16) u16 lds[65536];   // 128 KB

  // T1 XCD swizzle: nwg = 72*16 = 1152 = 8*144 (exact)
  const int f = blockIdx.y * MAXT1 + blockIdx.x;
  const int wg = (f & 7) * 144 + (f >> 3);
  const int tileIdx = wg % MAXT1;
  const int j = wg / MAXT1;                 // h cols [j*128,+128), g at +HH

  const int ts = tileIdx * 256;
  if (ts >= pofs[EE]) return;
  int e = 0;
#pragma unroll
  for (int i = 1; i < EE; ++i) e += (ts >= pofs[i]) ? 1 : 0;

  const int tid = threadIdx.x;
  const int w = tid >> 6, lane = tid & 63;
  const int wm = w >> 2, wn = w & 3;        // 2 x 4 waves

  const u16* bbase = w13t + (long)e * ((long)H2 * DD);

  // staging: per half-tile ht, 2 instrs i; 16B/lane. [128][64] region.
  int aoffg[2][2]; int boffg[2][2]; int dstA[2][2], dstB[2][2];
#pragma unroll
  for (int ht = 0; ht < 2; ++ht)
#pragma unroll
    for (int i = 0; i < 2; ++i) {
      const int L = tid * 16 + i * 8192;    // byte within region
      const int row = L >> 7;
      const int slot = ((L >> 4) & 7) ^ (row & 7);
      aoffg[ht][i] = ptok[ts + ht * 128 + row] * DD + slot * 8;
      const int r = ht * 128 + row;
      const int wnr = r >> 6, within = r & 63;
      const int grow = (within < 32) ? (j * 128 + wnr * 32 + within)
                                     : (HH + j * 128 + wnr * 32 + within - 32);
      boffg[ht][i] = grow * DD + slot * 8;
      dstA[ht][i] = ht * 8192 + i * 4096 + w * 512;            // + p*16384
      dstB[ht][i] = 32768 + ht * 8192 + i * 4096 + w * 512;
    }

  const int l15 = lane & 15, x7 = lane & 7, sA = lane >> 4;
  int aoff[2][8], boff[2][4];
#pragma unroll
  for (int kk = 0; kk < 2; ++kk) {
    const int sl = ((kk * 4 + sA) ^ x7) * 8;
#pragma unroll
    for (int m = 0; m < 8; ++m) aoff[kk][m] = (m * 16 + l15) * 64 + sl;
#pragma unroll
    for (int n = 0; n < 4; ++n) boff[kk][n] = ((w & 1) * 64 + n * 16 + l15) * 64 + sl;
  }

  f32x4 acc[8][4];
#pragma unroll
  for (int m = 0; m < 8; ++m)
#pragma unroll
    for (int n = 0; n < 4; ++n) acc[m][n] = (f32x4){0.f, 0.f, 0.f, 0.f};

  auto stageA = [&](int t, int p, int ht) {
    const int k0 = t * 64;
    gload_lds16(xb + aoffg[ht][0] + k0, lds + p * 16384 + dstA[ht][0]);
    gload_lds16(xb + aoffg[ht][1] + k0, lds + p * 16384 + dstA[ht][1]);
  };
  auto stageB = [&](int t, int p, int ht) {
    const int k0 = t * 64;
    gload_lds16(bbase + boffg[ht][0] + k0, lds + p * 16384 + dstB[ht][0]);
    gload_lds16(bbase + boffg[ht][1] + k0, lds + p * 16384 + dstB[ht][1]);
  };

  bf16x8 af[2][8], bf[2][4];

  // prologue: A(0),B(0),A(1) = 12 loads; vmcnt(4) -> K-tile 0 fully landed
  stageA(0, 0, 0); stageA(0, 0, 1); stageB(0, 0, 0); stageB(0, 0, 1);
  stageA(1, 1, 0); stageA(1, 1, 1);
  WAITV4(); BAR();

  for (int t = 0; t < 16; ++t) {
    const int p = t & 1;
    const bool stB = t < 15, stA = t < 14;
    const u16* Areg = lds + p * 16384 + wm * 8192;
    const u16* Breg = lds + 32768 + p * 16384 + (wn >> 1) * 8192;
    // ---- P0: ds a[0..3], b[0..1]; stage B0(t+1) ----
#pragma unroll
    for (int kk = 0; kk < 2; ++kk) {
#pragma unroll
      for (int m = 0; m < 4; ++m) af[kk][m] = *(const bf16x8*)(Areg + aoff[kk][m]);
#pragma unroll
      for (int n = 0; n < 2; ++n) bf[kk][n] = *(const bf16x8*)(Breg + boff[kk][n]);
    }
    if (stB) stageB(t + 1, p ^ 1, 0);
    BAR(); LGKM0();
    QUAD(0, 0);
    BAR();
    // ---- P1: ds a[4..7]; stage B1(t+1) ----
#pragma unroll
    for (int kk = 0; kk < 2; ++kk)
#pragma unroll
      for (int m = 4; m < 8; ++m) af[kk][m] = *(const bf16x8*)(Areg + aoff[kk][m]);
    if (stB) stageB(t + 1, p ^ 1, 1);
    BAR(); LGKM0();
    QUAD(4, 0);
    BAR();
    // ---- P2: ds b[2..3]; stage A0(t+2) ----
#pragma unroll
    for (int kk = 0; kk < 2; ++kk)
#pragma unroll
      for (int n = 2; n < 4; ++n) bf[kk][n] = *(const bf16x8*)(Breg + boff[kk][n]);
    if (stA) stageA(t + 2, p, 0);
    BAR(); LGKM0();
    QUAD(4, 2);
    BAR();
    // ---- P3: stage A1(t+2); tail vmcnt ----
    if (stA) stageA(t + 2, p, 1);
    BAR();
    QUAD(0, 2);
    if (t < 14) { WAITV4(); } else if (t == 14) { WAITV0(); }
    BAR();
  }

  // epilogue: silu(g)*h in registers (n and n+2 share output col)
#pragma unroll
  for (int m = 0; m < 8; ++m)
#pragma unroll
    for (int n = 0; n < 2; ++n) {
      const int col = j * 128 + wn * 32 + n * 16 + l15;
#pragma unroll
      for (int r = 0; r < 4; ++r) {
        const int row = ts + wm * 128 + m * 16 + sA * 4 + r;
        const float h = acc[m][n][r];
        const float g = acc[m][n + 2][r];
        hb[(long)row * HH + col] = f2bf(h * (g / (1.f + __expf(-g))));
      }
    }
}

// ============ GEMM2: R3-proven 128x128 2-barrier core ============
__global__ __launch_bounds__(256, 2)
void gemm2_kernel(const u16* __restrict__ hb, const u16* __restrict__ w2t,
                  const float* __restrict__ pscale, const int* __restrict__ pofs,
                  u16* __restrict__ ye) {
  __shared__ __align__(16) u16 lds_a[128 * 64];
  __shared__ __align__(16) u16 lds_b[128 * 64];

  // T1 XCD swizzle: nwg = 144*8 = 1152 = 8*144 (exact)
  const int f = blockIdx.y * MAXT2 + blockIdx.x;
  const int wg = (f & 7) * 144 + (f >> 3);
  const int tileIdx = wg % MAXT2;
  const int j = wg / MAXT2;                 // out cols [j*128, j*128+128)

  const int ts = tileIdx * 128;
  if (ts >= pofs[EE]) return;
  int e = 0;
#pragma unroll
  for (int i = 1; i < EE; ++i) e += (ts >= pofs[i]) ? 1 : 0;

  const int tid = threadIdx.x;
  const int w = tid >> 6, lane = tid & 63;
  const int wr = w >> 1, wc = w & 1;

  const u16* bbase = w2t + (long)e * ((long)DD * HH);

  const u16* asrc[4]; const u16* bsrc[4];
  u16* adst[4]; u16* bdst[4];
#pragma unroll
  for (int r = 0; r < 4; ++r) {
    const int L = (r * 4 + w) * 1024 + lane * 16;
    const int row = L >> 7;
    const int slot = ((L >> 4) & 7) ^ (row & 7);
    asrc[r] = hb + (long)(ts + row) * HH + slot * 8;
    bsrc[r] = bbase + (long)(j * 128 + row) * HH + slot * 8;
    adst[r] = lds_a + (r * 4 + w) * 512;
    bdst[r] = lds_b + (r * 4 + w) * 512;
  }

  const int rA = wr * 64 + (lane & 15);
  const int sA = lane >> 4;
  const int x7 = lane & 7;
  int aoff[2][4], boff[2][4];
#pragma unroll
  for (int kk = 0; kk < 2; ++kk) {
    const int sl = ((kk * 4 + sA) ^ x7) * 8;
#pragma unroll
    for (int m = 0; m < 4; ++m) aoff[kk][m] = (rA + m * 16) * 64 + sl;
#pragma unroll
    for (int n = 0; n < 4; ++n) boff[kk][n] = (wc * 64 + n * 16 + (lane & 15)) * 64 + sl;
  }

  f32x4 acc[4][4];
#pragma unroll
  for (int m = 0; m < 4; ++m)
#pragma unroll
    for (int n = 0; n < 4; ++n) acc[m][n] = (f32x4){0.f, 0.f, 0.f, 0.f};

  for (int k0 = 0; k0 < HH; k0 += 64) {
#pragma unroll
    for (int r = 0; r < 4; ++r) gload_lds16(asrc[r] + k0, adst[r]);
#pragma unroll
    for (int r = 0; r < 4; ++r) gload_lds16(bsrc[r] + k0, bdst[r]);
    __syncthreads();

    bf16x8 af[2][4], bfr[2][4];
#pragma unroll
    for (int kk = 0; kk < 2; ++kk) {
#pragma unroll
      for (int m = 0; m < 4; ++m) af[kk][m] = *(const bf16x8*)(lds_a + aoff[kk][m]);
#pragma unroll
      for (int n = 0; n < 4; ++n) bfr[kk][n] = *(const bf16x8*)(lds_b + boff[kk][n]);
    }
#pragma unroll
    for (int m = 0; m < 4; ++m)
#pragma unroll
      for (int n = 0; n < 4; ++n)
#pragma unroll
        for (int kk = 0; kk < 2; ++kk)
          acc[m][n] = __builtin_amdgcn_mfma_f32_16x16x32_bf16(af[kk][m], bfr[kk][n], acc[m][n], 0, 0, 0);
    __syncthreads();
  }

  const int rg = lane >> 4;
#pragma unroll
  for (int m = 0; m < 4; ++m)
#pragma unroll
    for (int r = 0; r < 4; ++r) {
      const int row = ts + wr * 64 + m * 16 + rg * 4 + r;
      const float sc = pscale[row];   // 0.0 for pad rows
#pragma unroll
      for (int n = 0; n < 4; ++n) {
        const int col = j * 128 + wc * 64 + n * 16 + (lane & 15);
        ye[(long)row * DD + col] = f2bf(acc[m][n][r] * sc);
      }
    }
}

// ---------------- combine: y[t] = ye[pos0] + ye[pos1] ----------------
__global__ void combine_kernel(const u16* __restrict__ ye, const int* __restrict__ ppos,
                               float* __restrict__ y) {
  const long i = (long)blockIdx.x * 256 + threadIdx.x;  // one thread -> 8 outputs
  const int t = (int)(i >> 7);
  const int c = ((int)i & 127) * 8;
  const int p0 = ppos[t * 2], p1 = ppos[t * 2 + 1];
  u16x8 v0 = *(const u16x8*)(ye + (long)p0 * DD + c);
  u16x8 v1 = *(const u16x8*)(ye + (long)p1 * DD + c);
  f32x4 o0, o1;
  o0[0] = bf2f(v0[0]) + bf2f(v1[0]);
  o0[1] = bf2f(v0[1]) + bf2f(v1[1]);
  o0[2] = bf2f(v0[2]) + bf2f(v1[2]);
  o0[3] = bf2f(v0[3]) + bf2f(v1[3]);
  o1[0] = bf2f(v0[4]) + bf2f(v1[4]);
  o1[1] = bf2f(v0[5]) + bf2f(v1[5]);
  o1[2] = bf2f(v0[6]) + bf2f(v1[6]);
  o1[3] = bf2f(v0[7]) + bf2f(v1[7]);
  *(f32x4*)(y + (long)t * DD + c) = o0;
  *(f32x4*)(y + (long)t * DD + c + 4) = o1;
}

extern "C" void kernel_launch(void* const* d_in, const int* in_sizes, int n_in,
                              void* d_out, int out_size, void* d_ws, size_t ws_size,
                              hipStream_t stream) {
  const float* x    = (const float*)d_in[0];
  const float* ep   = (const float*)d_in[1];
  const int*   eidx = (const int*)d_in[2];
  const float* w13  = (const float*)d_in[3];
  const float* w2   = (const float*)d_in[4];
  float* y = (float*)d_out;

  char* ws = (char*)d_ws;
  size_t off = 0;
  auto alloc = [&](size_t bytes) {
    char* p = ws + off;
    off = (off + bytes + 255) & ~(size_t)255;
    return p;
  };
  u16* xb     = (u16*)alloc((size_t)TT * DD * 2);
  u16* w13t   = (u16*)alloc((size_t)EE * H2 * DD * 2);
  u16* w2t    = (u16*)alloc((size_t)EE * DD * HH * 2);
  u16* hb     = (u16*)alloc((size_t)PADROWS * HH * 2);
  u16* ye     = (u16*)alloc((size_t)PADROWS * DD * 2);
  char* zbase = ws + off;
  int*   ptok   = (int*)alloc((size_t)PADROWS * 4);
  float* pscale = (float*)alloc((size_t)PADROWS * 4);
  int*   cnt    = (int*)alloc(EE * 4);
  int*   cnt2   = (int*)alloc(EE * 4);
  size_t zbytes = (size_t)((ws + off) - zbase);
  int*   pofs   = (int*)alloc((EE + 1) * 4);
  int*   ppos   = (int*)alloc((size_t)PP * 4);
  (void)ws_size; (void)in_sizes; (void)n_in; (void)out_size;

  // zero routing state (pad rows -> token 0, scale 0)
  hipMemsetAsync(zbase, 0, zbytes, stream);

  cast_x_kernel<<<4096, 256, 0, stream>>>(x, xb);
  // w13 [E][1024][4096] -> w13t [E][4096][1024]
  tcast_kernel<<<dim3(H2 / 32, DD / 128, EE), 256, 0, stream>>>(w13, w13t, DD, H2);
  // w2 [E][2048][1024] -> w2t [E][1024][2048]
  tcast_kernel<<<dim3(DD / 32, HH / 128, EE), 256, 0, stream>>>(w2, w2t, HH, DD);

  count_kernel<<<PP / 256, 256, 0, stream>>>(eidx, cnt);
  scan_kernel<<<1, 64, 0, stream>>>(cnt, pofs);
  place_kernel<<<PP / 256, 256, 0, stream>>>(eidx, ep, pofs, cnt2, ptok, pscale, ppos);

  gemm1_kernel<<<dim3(MAXT1, HH / 128), 512, 0, stream>>>(xb, w13t, ptok, pofs, hb);
  gemm2_kernel<<<dim3(MAXT2, DD / 128), 256, 0, stream>>>(hb, w2t, pscale, pofs, ye);
  combine_kernel<<<4096, 256, 0, stream>>>(ye, ppos, y);
}

// Round 6
// 475.458 us; speedup vs baseline: 1.0443x; 1.0054x over previous
//
#include <hip/hip_runtime.h>
#include <cstdint>
#include <cstddef>

// Problem constants (FusedExperts: E=8 TOPK=2, B=2 S=4096 D=1024 H=2048)
#define TT   8192     // tokens = B*S
#define DD   1024     // model dim
#define HH   2048     // hidden dim
#define H2   4096     // 2*H
#define EE   8        // experts
#define PP   16384    // routed pairs = TT*TOPK
#define PADROWS 18432 // max sum of per-expert 256-padded group sizes = 72*256
#define MAXT1 72      // 256-row tiles (gemm1)
#define MAXT2 144     // 128-row tiles (gemm2)

typedef unsigned short u16;
typedef __attribute__((ext_vector_type(8))) short bf16x8;   // 8 bf16 = 4 VGPR (MFMA A/B frag)
typedef __attribute__((ext_vector_type(8))) unsigned short u16x8;
typedef __attribute__((ext_vector_type(4))) float f32x4;    // MFMA C/D frag

__device__ __forceinline__ u16 f2bf(float f) {
  unsigned int u = __builtin_bit_cast(unsigned int, f);
  u += 0x7fffu + ((u >> 16) & 1u);          // round-to-nearest-even
  return (u16)(u >> 16);
}
__device__ __forceinline__ float bf2f(u16 s) {
  unsigned int u = ((unsigned int)s) << 16;
  return __builtin_bit_cast(float, u);
}

__device__ __forceinline__ void gload_lds16(const u16* g, u16* l) {
  __builtin_amdgcn_global_load_lds(
      (const __attribute__((address_space(1))) void*)g,
      (__attribute__((address_space(3))) void*)l, 16, 0, 0);
}

// m201-style sync: RAW barrier + bare waitcnt asm. NO sched_barrier(0) --
// m141: order-pinning defeats the compiler scheduler (510 vs 874 TF).
#define BAR()    __builtin_amdgcn_s_barrier()
#define LGKM0()  asm volatile("s_waitcnt lgkmcnt(0)")
#define WAITV4() asm volatile("s_waitcnt vmcnt(4)" ::: "memory")
#define WAITV0() asm volatile("s_waitcnt vmcnt(0)" ::: "memory")

// ---------------- casts ----------------
__global__ void cast_x_kernel(const float* __restrict__ x, u16* __restrict__ xb) {
  const long i = (long)blockIdx.x * 256 + threadIdx.x;  // one thread -> 8 elems
  const f32x4* s = (const f32x4*)(x + i * 8);
  f32x4 a = s[0], b = s[1];
  u16x8 o;
  o[0]=f2bf(a[0]); o[1]=f2bf(a[1]); o[2]=f2bf(a[2]); o[3]=f2bf(a[3]);
  o[4]=f2bf(b[0]); o[5]=f2bf(b[1]); o[6]=f2bf(b[2]); o[7]=f2bf(b[3]);
  *(u16x8*)(xb + i * 8) = o;
}

// src [E][R][C] f32 -> dst [E][C][R] bf16, vectorized 256B-contiguous writes.
__global__ void tcast_kernel(const float* __restrict__ src, u16* __restrict__ dst,
                             int R, int C) {
  __shared__ __align__(16) u16 tile[32][140];
  const long base = (long)blockIdx.z * (long)R * C;
  const int c0 = blockIdx.x * 32, r0 = blockIdx.y * 128;
  const int t = threadIdx.x;
  {
    const int tx = t & 31;          // col
    const int ty = t >> 5;          // row 0..7 (+8*rr)
#pragma unroll
    for (int rr = 0; rr < 16; ++rr) {
      const int r = ty + rr * 8;
      tile[tx][r] = f2bf(src[base + (long)(r0 + r) * C + c0 + tx]);
    }
  }
  __syncthreads();
  {
    const int k = t & 15;           // chunk within row: r8 = 8k
    const int cb = t >> 4;          // 0..15
#pragma unroll
    for (int i = 0; i < 2; ++i) {
      const int c = i * 16 + cb;
      u16x8 o = *(const u16x8*)(&tile[c][8 * k]);
      *(u16x8*)(dst + base + (long)(c0 + c) * R + r0 + 8 * k) = o;
    }
  }
}

// ---------------- routing ----------------
__global__ void count_kernel(const int* __restrict__ eidx, int* __restrict__ cnt) {
  int i = blockIdx.x * 256 + threadIdx.x;
  if (i < PP) atomicAdd(&cnt[eidx[i]], 1);
}
__global__ void scan_kernel(const int* __restrict__ cnt, int* __restrict__ pofs) {
  if (threadIdx.x == 0 && blockIdx.x == 0) {
    int run = 0;
    for (int e = 0; e < EE; ++e) { pofs[e] = run; run += ((cnt[e] + 255) >> 8) << 8; }
    pofs[EE] = run;
  }
}
__global__ void place_kernel(const int* __restrict__ eidx, const float* __restrict__ p,
                             const int* __restrict__ pofs, int* __restrict__ cnt2,
                             int* __restrict__ ptok, float* __restrict__ pscale,
                             int* __restrict__ ppos) {
  int i = blockIdx.x * 256 + threadIdx.x;
  if (i < PP) {
    int e = eidx[i];
    int r = atomicAdd(&cnt2[e], 1);
    int pos = pofs[e] + r;
    ptok[pos] = i >> 1;       // token index (TOPK=2)
    pscale[pos] = p[i];
    ppos[i] = pos;
  }
}

// ============ GEMM1: 256x256 8-phase schedule (m201 template port, unpinned) ============
// BM=256 rows, B-tile = 256 rows of w13t (128 h + 128 g, interleaved in 32-col
// stripes per wave), BK=64, 512 threads = 2(M) x 4(N) waves, per-wave 128x64.
// LDS 128KB: A[p][ht]=[128][64] swz, B[p][ht] likewise at +32768 (u16 units).
// Swizzle: (row,slot) stored at slot^(row&7); gload_lds linear dest + inverse-
// swizzled global source; ds_read applies same XOR (proven R2-R3).
// Phases per K-tile t (p=t&1): P0{ds a03,b01; stage B0(t+1)->p^1} P1{ds a47;
// stage B1(t+1)} P2{ds b23; stage A0(t+2)->p} P3{stage A1(t+2); vmcnt(4)}.
// Each phase: issue -> barrier -> lgkmcnt(0) -> prio1 -> 16 MFMA -> prio0 -> barrier.
// FIFO ledger: at t.P3 tail, waiting vmcnt(4) retires ...B1(t+1); leaves A(t+2).
#define QUAD(M0, N0) do {                                                        \
    __builtin_amdgcn_s_setprio(1);                                               \
    _Pragma("unroll") for (int mm = 0; mm < 4; ++mm)                             \
    _Pragma("unroll") for (int nn = 0; nn < 2; ++nn)                             \
    _Pragma("unroll") for (int kk = 0; kk < 2; ++kk)                             \
      acc[(M0)+mm][(N0)+nn] = __builtin_amdgcn_mfma_f32_16x16x32_bf16(           \
          af[kk][(M0)+mm], bf[kk][(N0)+nn], acc[(M0)+mm][(N0)+nn], 0, 0, 0);     \
    __builtin_amdgcn_s_setprio(0);                                               \
  } while (0)

__global__ __launch_bounds__(512, 2)
void gemm1_kernel(const u16* __restrict__ xb, const u16* __restrict__ w13t,
                  const int* __restrict__ ptok, const int* __restrict__ pofs,
                  u16* __restrict__ hb) {
  __shared__ __align__(16) u16 lds[65536];   // 128 KB

  // T1 XCD swizzle: nwg = 72*16 = 1152 = 8*144 (exact)
  const int f = blockIdx.y * MAXT1 + blockIdx.x;
  const int wg = (f & 7) * 144 + (f >> 3);
  const int tileIdx = wg % MAXT1;
  const int j = wg / MAXT1;                 // h cols [j*128,+128), g at +HH

  const int ts = tileIdx * 256;
  if (ts >= pofs[EE]) return;
  int e = 0;
#pragma unroll
  for (int i = 1; i < EE; ++i) e += (ts >= pofs[i]) ? 1 : 0;

  const int tid = threadIdx.x;
  const int w = tid >> 6, lane = tid & 63;
  const int wm = w >> 2, wn = w & 3;        // 2 x 4 waves

  const u16* bbase = w13t + (long)e * ((long)H2 * DD);

  // staging: per half-tile ht, 2 instrs i; 16B/lane. [128][64] region.
  int aoffg[2][2]; int boffg[2][2]; int dstA[2][2], dstB[2][2];
#pragma unroll
  for (int ht = 0; ht < 2; ++ht)
#pragma unroll
    for (int i = 0; i < 2; ++i) {
      const int L = tid * 16 + i * 8192;    // byte within region
      const int row = L >> 7;
      const int slot = ((L >> 4) & 7) ^ (row & 7);
      aoffg[ht][i] = ptok[ts + ht * 128 + row] * DD + slot * 8;
      const int r = ht * 128 + row;
      const int wnr = r >> 6, within = r & 63;
      const int grow = (within < 32) ? (j * 128 + wnr * 32 + within)
                                     : (HH + j * 128 + wnr * 32 + within - 32);
      boffg[ht][i] = grow * DD + slot * 8;
      dstA[ht][i] = ht * 8192 + i * 4096 + w * 512;            // + p*16384
      dstB[ht][i] = 32768 + ht * 8192 + i * 4096 + w * 512;
    }

  const int l15 = lane & 15, x7 = lane & 7, sA = lane >> 4;
  int aoff[2][8], boff[2][4];
#pragma unroll
  for (int kk = 0; kk < 2; ++kk) {
    const int sl = ((kk * 4 + sA) ^ x7) * 8;
#pragma unroll
    for (int m = 0; m < 8; ++m) aoff[kk][m] = (m * 16 + l15) * 64 + sl;
#pragma unroll
    for (int n = 0; n < 4; ++n) boff[kk][n] = ((w & 1) * 64 + n * 16 + l15) * 64 + sl;
  }

  f32x4 acc[8][4];
#pragma unroll
  for (int m = 0; m < 8; ++m)
#pragma unroll
    for (int n = 0; n < 4; ++n) acc[m][n] = (f32x4){0.f, 0.f, 0.f, 0.f};

  auto stageA = [&](int t, int p, int ht) {
    const int k0 = t * 64;
    gload_lds16(xb + aoffg[ht][0] + k0, lds + p * 16384 + dstA[ht][0]);
    gload_lds16(xb + aoffg[ht][1] + k0, lds + p * 16384 + dstA[ht][1]);
  };
  auto stageB = [&](int t, int p, int ht) {
    const int k0 = t * 64;
    gload_lds16(bbase + boffg[ht][0] + k0, lds + p * 16384 + dstB[ht][0]);
    gload_lds16(bbase + boffg[ht][1] + k0, lds + p * 16384 + dstB[ht][1]);
  };

  bf16x8 af[2][8], bf[2][4];

  // prologue: A(0),B(0),A(1) = 12 loads; vmcnt(4) -> K-tile 0 fully landed
  stageA(0, 0, 0); stageA(0, 0, 1); stageB(0, 0, 0); stageB(0, 0, 1);
  stageA(1, 1, 0); stageA(1, 1, 1);
  WAITV4(); BAR();

  for (int t = 0; t < 16; ++t) {
    const int p = t & 1;
    const bool stB = t < 15, stA = t < 14;
    const u16* Areg = lds + p * 16384 + wm * 8192;
    const u16* Breg = lds + 32768 + p * 16384 + (wn >> 1) * 8192;
    // ---- P0: ds a[0..3], b[0..1]; stage B0(t+1) ----
#pragma unroll
    for (int kk = 0; kk < 2; ++kk) {
#pragma unroll
      for (int m = 0; m < 4; ++m) af[kk][m] = *(const bf16x8*)(Areg + aoff[kk][m]);
#pragma unroll
      for (int n = 0; n < 2; ++n) bf[kk][n] = *(const bf16x8*)(Breg + boff[kk][n]);
    }
    if (stB) stageB(t + 1, p ^ 1, 0);
    BAR(); LGKM0();
    QUAD(0, 0);
    BAR();
    // ---- P1: ds a[4..7]; stage B1(t+1) ----
#pragma unroll
    for (int kk = 0; kk < 2; ++kk)
#pragma unroll
      for (int m = 4; m < 8; ++m) af[kk][m] = *(const bf16x8*)(Areg + aoff[kk][m]);
    if (stB) stageB(t + 1, p ^ 1, 1);
    BAR(); LGKM0();
    QUAD(4, 0);
    BAR();
    // ---- P2: ds b[2..3]; stage A0(t+2) ----
#pragma unroll
    for (int kk = 0; kk < 2; ++kk)
#pragma unroll
      for (int n = 2; n < 4; ++n) bf[kk][n] = *(const bf16x8*)(Breg + boff[kk][n]);
    if (stA) stageA(t + 2, p, 0);
    BAR(); LGKM0();
    QUAD(4, 2);
    BAR();
    // ---- P3: stage A1(t+2); tail vmcnt ----
    if (stA) stageA(t + 2, p, 1);
    BAR();
    QUAD(0, 2);
    if (t < 14) { WAITV4(); } else if (t == 14) { WAITV0(); }
    BAR();
  }

  // epilogue: silu(g)*h in registers (n and n+2 share output col)
#pragma unroll
  for (int m = 0; m < 8; ++m)
#pragma unroll
    for (int n = 0; n < 2; ++n) {
      const int col = j * 128 + wn * 32 + n * 16 + l15;
#pragma unroll
      for (int r = 0; r < 4; ++r) {
        const int row = ts + wm * 128 + m * 16 + sA * 4 + r;
        const float h = acc[m][n][r];
        const float g = acc[m][n + 2][r];
        hb[(long)row * HH + col] = f2bf(h * (g / (1.f + __expf(-g))));
      }
    }
}

// ============ GEMM2: R3-proven 128x128 2-barrier core ============
__global__ __launch_bounds__(256, 2)
void gemm2_kernel(const u16* __restrict__ hb, const u16* __restrict__ w2t,
                  const float* __restrict__ pscale, const int* __restrict__ pofs,
                  u16* __restrict__ ye) {
  __shared__ __align__(16) u16 lds_a[128 * 64];
  __shared__ __align__(16) u16 lds_b[128 * 64];

  // T1 XCD swizzle: nwg = 144*8 = 1152 = 8*144 (exact)
  const int f = blockIdx.y * MAXT2 + blockIdx.x;
  const int wg = (f & 7) * 144 + (f >> 3);
  const int tileIdx = wg % MAXT2;
  const int j = wg / MAXT2;                 // out cols [j*128, j*128+128)

  const int ts = tileIdx * 128;
  if (ts >= pofs[EE]) return;
  int e = 0;
#pragma unroll
  for (int i = 1; i < EE; ++i) e += (ts >= pofs[i]) ? 1 : 0;

  const int tid = threadIdx.x;
  const int w = tid >> 6, lane = tid & 63;
  const int wr = w >> 1, wc = w & 1;

  const u16* bbase = w2t + (long)e * ((long)DD * HH);

  const u16* asrc[4]; const u16* bsrc[4];
  u16* adst[4]; u16* bdst[4];
#pragma unroll
  for (int r = 0; r < 4; ++r) {
    const int L = (r * 4 + w) * 1024 + lane * 16;
    const int row = L >> 7;
    const int slot = ((L >> 4) & 7) ^ (row & 7);
    asrc[r] = hb + (long)(ts + row) * HH + slot * 8;
    bsrc[r] = bbase + (long)(j * 128 + row) * HH + slot * 8;
    adst[r] = lds_a + (r * 4 + w) * 512;
    bdst[r] = lds_b + (r * 4 + w) * 512;
  }

  const int rA = wr * 64 + (lane & 15);
  const int sA = lane >> 4;
  const int x7 = lane & 7;
  int aoff[2][4], boff[2][4];
#pragma unroll
  for (int kk = 0; kk < 2; ++kk) {
    const int sl = ((kk * 4 + sA) ^ x7) * 8;
#pragma unroll
    for (int m = 0; m < 4; ++m) aoff[kk][m] = (rA + m * 16) * 64 + sl;
#pragma unroll
    for (int n = 0; n < 4; ++n) boff[kk][n] = (wc * 64 + n * 16 + (lane & 15)) * 64 + sl;
  }

  f32x4 acc[4][4];
#pragma unroll
  for (int m = 0; m < 4; ++m)
#pragma unroll
    for (int n = 0; n < 4; ++n) acc[m][n] = (f32x4){0.f, 0.f, 0.f, 0.f};

  for (int k0 = 0; k0 < HH; k0 += 64) {
#pragma unroll
    for (int r = 0; r < 4; ++r) gload_lds16(asrc[r] + k0, adst[r]);
#pragma unroll
    for (int r = 0; r < 4; ++r) gload_lds16(bsrc[r] + k0, bdst[r]);
    __syncthreads();

    bf16x8 af[2][4], bfr[2][4];
#pragma unroll
    for (int kk = 0; kk < 2; ++kk) {
#pragma unroll
      for (int m = 0; m < 4; ++m) af[kk][m] = *(const bf16x8*)(lds_a + aoff[kk][m]);
#pragma unroll
      for (int n = 0; n < 4; ++n) bfr[kk][n] = *(const bf16x8*)(lds_b + boff[kk][n]);
    }
#pragma unroll
    for (int m = 0; m < 4; ++m)
#pragma unroll
      for (int n = 0; n < 4; ++n)
#pragma unroll
        for (int kk = 0; kk < 2; ++kk)
          acc[m][n] = __builtin_amdgcn_mfma_f32_16x16x32_bf16(af[kk][m], bfr[kk][n], acc[m][n], 0, 0, 0);
    __syncthreads();
  }

  const int rg = lane >> 4;
#pragma unroll
  for (int m = 0; m < 4; ++m)
#pragma unroll
    for (int r = 0; r < 4; ++r) {
      const int row = ts + wr * 64 + m * 16 + rg * 4 + r;
      const float sc = pscale[row];   // 0.0 for pad rows
#pragma unroll
      for (int n = 0; n < 4; ++n) {
        const int col = j * 128 + wc * 64 + n * 16 + (lane & 15);
        ye[(long)row * DD + col] = f2bf(acc[m][n][r] * sc);
      }
    }
}

// ---------------- combine: y[t] = ye[pos0] + ye[pos1] ----------------
__global__ void combine_kernel(const u16* __restrict__ ye, const int* __restrict__ ppos,
                               float* __restrict__ y) {
  const long i = (long)blockIdx.x * 256 + threadIdx.x;  // one thread -> 8 outputs
  const int t = (int)(i >> 7);
  const int c = ((int)i & 127) * 8;
  const int p0 = ppos[t * 2], p1 = ppos[t * 2 + 1];
  u16x8 v0 = *(const u16x8*)(ye + (long)p0 * DD + c);
  u16x8 v1 = *(const u16x8*)(ye + (long)p1 * DD + c);
  f32x4 o0, o1;
  o0[0] = bf2f(v0[0]) + bf2f(v1[0]);
  o0[1] = bf2f(v0[1]) + bf2f(v1[1]);
  o0[2] = bf2f(v0[2]) + bf2f(v1[2]);
  o0[3] = bf2f(v0[3]) + bf2f(v1[3]);
  o1[0] = bf2f(v0[4]) + bf2f(v1[4]);
  o1[1] = bf2f(v0[5]) + bf2f(v1[5]);
  o1[2] = bf2f(v0[6]) + bf2f(v1[6]);
  o1[3] = bf2f(v0[7]) + bf2f(v1[7]);
  *(f32x4*)(y + (long)t * DD + c) = o0;
  *(f32x4*)(y + (long)t * DD + c + 4) = o1;
}

extern "C" void kernel_launch(void* const* d_in, const int* in_sizes, int n_in,
                              void* d_out, int out_size, void* d_ws, size_t ws_size,
                              hipStream_t stream) {
  const float* x    = (const float*)d_in[0];
  const float* ep   = (const float*)d_in[1];
  const int*   eidx = (const int*)d_in[2];
  const float* w13  = (const float*)d_in[3];
  const float* w2   = (const float*)d_in[4];
  float* y = (float*)d_out;

  char* ws = (char*)d_ws;
  size_t off = 0;
  auto alloc = [&](size_t bytes) {
    char* p = ws + off;
    off = (off + bytes + 255) & ~(size_t)255;
    return p;
  };
  u16* xb     = (u16*)alloc((size_t)TT * DD * 2);
  u16* w13t   = (u16*)alloc((size_t)EE * H2 * DD * 2);
  u16* w2t    = (u16*)alloc((size_t)EE * DD * HH * 2);
  u16* hb     = (u16*)alloc((size_t)PADROWS * HH * 2);
  u16* ye     = (u16*)alloc((size_t)PADROWS * DD * 2);
  char* zbase = ws + off;
  int*   ptok   = (int*)alloc((size_t)PADROWS * 4);
  float* pscale = (float*)alloc((size_t)PADROWS * 4);
  int*   cnt    = (int*)alloc(EE * 4);
  int*   cnt2   = (int*)alloc(EE * 4);
  size_t zbytes = (size_t)((ws + off) - zbase);
  int*   pofs   = (int*)alloc((EE + 1) * 4);
  int*   ppos   = (int*)alloc((size_t)PP * 4);
  (void)ws_size; (void)in_sizes; (void)n_in; (void)out_size;

  // zero routing state (pad rows -> token 0, scale 0)
  hipMemsetAsync(zbase, 0, zbytes, stream);

  cast_x_kernel<<<4096, 256, 0, stream>>>(x, xb);
  // w13 [E][1024][4096] -> w13t [E][4096][1024]
  tcast_kernel<<<dim3(H2 / 32, DD / 128, EE), 256, 0, stream>>>(w13, w13t, DD, H2);
  // w2 [E][2048][1024] -> w2t [E][1024][2048]
  tcast_kernel<<<dim3(DD / 32, HH / 128, EE), 256, 0, stream>>>(w2, w2t, HH, DD);

  count_kernel<<<PP / 256, 256, 0, stream>>>(eidx, cnt);
  scan_kernel<<<1, 64, 0, stream>>>(cnt, pofs);
  place_kernel<<<PP / 256, 256, 0, stream>>>(eidx, ep, pofs, cnt2, ptok, pscale, ppos);

  gemm1_kernel<<<dim3(MAXT1, HH / 128), 512, 0, stream>>>(xb, w13t, ptok, pofs, hb);
  gemm2_kernel<<<dim3(MAXT2, DD / 128), 256, 0, stream>>>(hb, w2t, pscale, pofs, ye);
  combine_kernel<<<4096, 256, 0, stream>>>(ye, ppos, y);
}